// Round 3
// baseline (207.324 us; speedup 1.0000x reference)
//
#include <hip/hip_runtime.h>
#include <hip/hip_bf16.h>
#include <stdint.h>

typedef unsigned short u16;
typedef unsigned int   u32;

#define N_DIM  1024
#define IN_DIM 1024
#define H_DIM  64
#define BATCH  16

typedef __bf16 bf16x8 __attribute__((ext_vector_type(8)));
typedef float  f32x4  __attribute__((ext_vector_type(4)));

// round-to-nearest-even fp32 -> bf16 (bit pattern)
__device__ inline u16 f2bf(float f) {
    union { float f; u32 u; } v; v.f = f;
    u32 u = v.u;
    return (u16)((u + 0x7fffu + ((u >> 16) & 1u)) >> 16);
}
// packed pair: v_cvt_pk_bf16_f32 when available
__device__ inline u32 pack2(float a, float b) {
    __hip_bfloat162 h = __float22bfloat162_rn(float2{a, b});
    union { __hip_bfloat162 h; u32 u; } cv; cv.h = h; return cv.u;
}

// async global->LDS, 16B per lane. LDS dest must be wave-uniform base + lane*16.
__device__ inline void gl_lds16(const u16* g, u16* l) {
    __builtin_amdgcn_global_load_lds(
        (const __attribute__((address_space(1))) u32*)g,
        (__attribute__((address_space(3))) u32*)l, 16, 0, 0);
}

// ---------------------------------------------------------------------------
// prep (merged): blocks 0..255 = G transpose tiles + per-jtile rowsum partials
//                blocks 256..767 = Q/Kw transpose-cast
__global__ __launch_bounds__(256) void prep(
        const float* __restrict__ G, const float* __restrict__ Q,
        const float* __restrict__ Kw, u16* __restrict__ Gbt,
        float* __restrict__ Grp, u16* __restrict__ QT, u16* __restrict__ KwT) {
    int bid = blockIdx.x;
    if (bid >= 256) {
        int idx = (bid - 256) * 256 + threadIdx.x;      // 0 .. 131071
        const float* src = (idx < 65536) ? Q : Kw;
        u16* dst = (idx < 65536) ? QT : KwT;
        int i = idx & 65535;
        int h = i >> 10;         // 0..63
        int n = i & 1023;        // 0..1023 (contiguous store)
        dst[h * 1024 + n] = f2bf(src[n * 64 + h]);
        return;
    }
    __shared__ float tile[64][65];
    int jt = bid & 15, it = bid >> 4;
    int i0 = it * 64, j0 = jt * 64;
    int tx = threadIdx.x & 63, ty = threadIdx.x >> 6;   // ty 0..3
    for (int r = 0; r < 16; ++r) {
        int i = ty * 16 + r;
        tile[i][tx] = G[(size_t)(i0 + i) * 1024 + j0 + tx];
    }
    __syncthreads();
    for (int r = 0; r < 16; ++r) {
        int j = ty * 16 + r;
        Gbt[(size_t)(j0 + j) * 1024 + i0 + tx] = f2bf(tile[tx][j]);
    }
    if (ty == 0) {
        float sum = 0.f;
        for (int j = 0; j < 64; ++j) sum += tile[tx][j];
        Grp[jt * 1024 + i0 + tx] = sum;                 // plain store, no atomics
    }
}

// ---------------------------------------------------------------------------
// qkt (merged): z==0 -> q[b][n][h] = sum_i s[n][b][i] Qw[i][h]
//               z==1 -> kt[b][i][h] = sum_n s[n][b][i] Kw[n][h]
__global__ __launch_bounds__(512, 4) void qkt(
        const float* __restrict__ s, const u16* __restrict__ QT,
        const u16* __restrict__ KwT, const float* __restrict__ Grp,
        u16* __restrict__ qws, u16* __restrict__ ktws, float* __restrict__ Grsum) {
    int b = blockIdx.y;
    int t = threadIdx.x, lane = t & 63, w = t >> 6, quad = lane >> 4, l15 = lane & 15;
    __shared__ __align__(16) u16 sh[2][2][64][34];     // kt staging; q aliases as 16KB reduce
    float* red = (float*)sh;

    if (blockIdx.z == 0) {
        // ---------------- q role ----------------
        if (blockIdx.y == 0 && t < 64) {               // Grsum finalize (16 x-blocks cover 1024 i)
            int i = blockIdx.x * 64 + t;
            float g = 0.f;
            for (int jt = 0; jt < 16; ++jt) g += Grp[jt * 1024 + i];
            Grsum[i] = g;
        }
        int n0 = blockIdx.x * 64;
        int wm = (w & 3) * 16;                         // m-quarter within 64
        int kb = (w >> 2) * 512;                       // k-half
        const float* arow = s + (size_t)(n0 + wm + l15) * (BATCH * IN_DIM)
                              + (size_t)b * IN_DIM + kb + quad * 8;
        const u16* bbase = QT + (size_t)l15 * 1024 + kb + quad * 8;

        f32x4 acc[4] = {};
        float4 A0[3], A1[3];
        bf16x8 Bf[2][4];
        A0[0] = ((const float4*)arow)[0];
        A1[0] = ((const float4*)arow)[1];
        A0[1] = ((const float4*)(arow + 32))[0];
        A1[1] = ((const float4*)(arow + 32))[1];
#pragma unroll
        for (int ct = 0; ct < 4; ++ct)
            Bf[0][ct] = *(const bf16x8*)&bbase[ct * 16384];

#pragma unroll
        for (int st = 0; st < 16; ++st) {              // 16 steps of k=32
            int cur = st % 3, cb = st & 1;
            if (st < 14) {                             // A prefetch depth 3 (HBM)
                const float4* ap = (const float4*)(arow + (size_t)(st + 2) * 32);
                A0[(st + 2) % 3] = ap[0];
                A1[(st + 2) % 3] = ap[1];
            }
            if (st < 15) {                             // B prefetch depth 2 (L2)
#pragma unroll
                for (int ct = 0; ct < 4; ++ct)
                    Bf[cb ^ 1][ct] = *(const bf16x8*)&bbase[ct * 16384 + (st + 1) * 32];
            }
            float4 fa = A0[cur], fb = A1[cur];
            union { uint4 u; bf16x8 v; } cu;
            cu.u = (uint4){ pack2(fa.x, fa.y), pack2(fa.z, fa.w),
                            pack2(fb.x, fb.y), pack2(fb.z, fb.w) };
#pragma unroll
            for (int ct = 0; ct < 4; ++ct)
                acc[ct] = __builtin_amdgcn_mfma_f32_16x16x32_bf16(cu.v, Bf[cb][ct], acc[ct], 0, 0, 0);
        }

        // cross-k-half reduce through LDS
        if (w >= 4) {
            float* dst = red + ((w - 4) * 64 + lane) * 16;
#pragma unroll
            for (int ct = 0; ct < 4; ++ct) *(f32x4*)&dst[ct * 4] = acc[ct];
        }
        __syncthreads();
        if (w < 4) {
            const float* sp2 = red + (w * 64 + lane) * 16;
            u16* ob = qws + (size_t)b * 65536;
#pragma unroll
            for (int ct = 0; ct < 4; ++ct) {
                f32x4 o = *(const f32x4*)&sp2[ct * 4];
#pragma unroll
                for (int r = 0; r < 4; ++r) {
                    int m = n0 + wm + quad * 4 + r;
                    ob[(size_t)m * 64 + ct * 16 + l15] = f2bf(acc[ct][r] + o[r]);
                }
            }
        }
        return;
    }

    // ---------------- kt role ----------------
    int i0 = blockIdx.x * 64;
    int half = w >> 2;                                 // compute n-half
    int wm = (w & 3) * 16;                             // i-quarter
    int shalf = t >> 8, nr = (t & 255) >> 3, iofs = (t & 7) * 8;  // staging role
    const float* sp = s + (size_t)(shalf * 512 + nr) * (BATCH * IN_DIM)
                        + (size_t)b * IN_DIM + i0 + iofs;
    const u16* bbase = KwT + (size_t)l15 * 1024 + half * 512 + quad * 8;

    f32x4 acc[4] = {};
    float4 P0[2], P1[2];
    bf16x8 Bf[2][4];
    P0[0] = ((const float4*)sp)[0];
    P1[0] = ((const float4*)sp)[1];
    {
        const float4* p = (const float4*)(sp + (size_t)32 * 16384);
        P0[1] = p[0]; P1[1] = p[1];
    }
#pragma unroll
    for (int ct = 0; ct < 4; ++ct)
        Bf[0][ct] = *(const bf16x8*)&bbase[ct * 16384];

#pragma unroll
    for (int c = 0; c < 16; ++c) {                     // 16 chunks of n=32 per half
        int buf = c & 1;
        float4 fa = P0[buf], fb = P1[buf];
        u16* wp = &sh[shalf][buf][iofs][nr];
        wp[0]   = f2bf(fa.x);
        wp[34]  = f2bf(fa.y);
        wp[68]  = f2bf(fa.z);
        wp[102] = f2bf(fa.w);
        wp[136] = f2bf(fb.x);
        wp[170] = f2bf(fb.y);
        wp[204] = f2bf(fb.z);
        wp[238] = f2bf(fb.w);
        __syncthreads();                               // buf ready (both halves)
        if (c < 14) {                                  // prefetch chunk c+2 (HBM/L3)
            const float4* p = (const float4*)(sp + (size_t)(c + 2) * 32 * 16384);
            P0[buf] = p[0]; P1[buf] = p[1];
        }
        if (c < 15) {                                  // prefetch next B-frags (L2)
#pragma unroll
            for (int ct = 0; ct < 4; ++ct)
                Bf[(c + 1) & 1][ct] = *(const bf16x8*)&bbase[ct * 16384 + (c + 1) * 32];
        }
        const u32* ap = (const u32*)&sh[half][buf][wm + l15][quad * 8];
        union { u32 u[4]; bf16x8 v; } au;
        au.u[0] = ap[0]; au.u[1] = ap[1]; au.u[2] = ap[2]; au.u[3] = ap[3];
#pragma unroll
        for (int ct = 0; ct < 4; ++ct)
            acc[ct] = __builtin_amdgcn_mfma_f32_16x16x32_bf16(au.v, Bf[buf][ct], acc[ct], 0, 0, 0);
    }

    __syncthreads();                                   // staging reads all done
    if (w >= 4) {
        float* dst = red + ((w - 4) * 64 + lane) * 16;
#pragma unroll
        for (int ct = 0; ct < 4; ++ct) *(f32x4*)&dst[ct * 4] = acc[ct];
    }
    __syncthreads();
    if (w < 4) {
        const float* sp2 = red + (w * 64 + lane) * 16;
        u16* ob = ktws + (size_t)b * 65536;
#pragma unroll
        for (int ct = 0; ct < 4; ++ct) {
            f32x4 o = *(const f32x4*)&sp2[ct * 4];
#pragma unroll
            for (int r = 0; r < 4; ++r) {
                int i = i0 + wm + quad * 4 + r;
                ob[(size_t)i * 64 + ct * 16 + l15] = f2bf(acc[ct][r] + o[r]);
            }
        }
    }
}

// ---------------------------------------------------------------------------
// gemm_fused (restructured, wave-exclusive m-rows):
// Per (b, m-tile 128, n-tile 256), 4 waves; wave w owns m-rows [w*32, w*32+32).
// Per K-step (32 i): score S^T(32i x 32m) = kt_chunk @ q^T (8 MFMA, kt loaded
// DIRECTLY from global/L2, 1-iter register prefetch), square(+1e-9), Grs-weighted
// rowsum (wave-private), pack bf16 -> As (wave-private rows, intra-wave handoff,
// DS-pipe in-order => NO barrier), then agg: acc += As(32x32) @ Bs(256x32).
// ONE __syncthreads per K-step (Bs gl_lds double-buffer). Rowsum needs no
// atomics (m-rows wave-exclusive). ktc/rs/barrier2 of the old design deleted.
__global__ __launch_bounds__(256, 2) void gemm_fused(
        const u16* __restrict__ qws, const u16* __restrict__ ktws,
        const u16* __restrict__ Gbt, const float* __restrict__ Grsum,
        float* __restrict__ out) {
    int b = blockIdx.z;
    int n0 = blockIdx.x * 256, m0 = blockIdx.y * 128;
    const u16* qb = qws  + (size_t)b * 65536;
    const u16* kb = ktws + (size_t)b * 65536;
    __shared__ __align__(16) u16 As[128 * 40];       // score->agg, wave-private rows
    __shared__ __align__(16) u16 Bs[2][256 * 32];    // Gbt staging (gl_lds, dbuf, linear)
    __shared__ __align__(16) float Grs[1024];
    __shared__ float rsw[128];                       // per-row inverse sums (wave-private)
    int t = threadIdx.x, lane = t & 63, w = t >> 6, quad = lane >> 4, l15 = lane & 15;
    int wm = w * 32;                                 // wave's m-rows [wm, wm+32)

    ((float4*)Grs)[t] = ((const float4*)Grsum)[t];

    // K-invariant q B-frags: B[k=h][col=m] for the wave's 32 m-rows
    bf16x8 qf[2][2];
#pragma unroll
    for (int jm = 0; jm < 2; ++jm)
#pragma unroll
        for (int kick = 0; kick < 2; ++kick)
            qf[jm][kick] = *(const bf16x8*)&qb[(size_t)(m0 + wm + jm*16 + l15) * 64 + kick*32 + quad*8];

    // iter-0 Bs staging: Gbt rows n0..n0+255, cols 0..31
    int br = t >> 2, bc = (t & 3) * 8;
#pragma unroll
    for (int g4 = 0; g4 < 4; ++g4)
        gl_lds16(Gbt + (size_t)(n0 + br + g4*64) * 1024 + bc, &Bs[0][(br + g4*64) * 32 + bc]);

    // iter-0 kt A-frags (direct from global, L2-resident)
    bf16x8 kc[2][2], kn[2][2];
#pragma unroll
    for (int it = 0; it < 2; ++it)
#pragma unroll
        for (int kick = 0; kick < 2; ++kick)
            kc[it][kick] = *(const bf16x8*)&kb[(size_t)(it*16 + l15) * 64 + kick*32 + quad*8];

    f32x4 acc[2][16] = {};
    float partial[2] = {0.f, 0.f};

    for (int kk = 0; kk < 32; ++kk) {
        int buf = kk & 1;
        __syncthreads();                           // Bs[buf] ready; buf^1 free for prefetch
        if (kk < 31) {                             // prefetch next Gbt chunk (lands by next sync)
#pragma unroll
            for (int g4 = 0; g4 < 4; ++g4)
                gl_lds16(Gbt + (size_t)(n0 + br + g4*64) * 1024 + (kk+1)*32 + bc,
                         &Bs[buf^1][(br + g4*64) * 32 + bc]);
        }
        // ---- score: S^T[i 32][m 32] for the wave's rows
        f32x4 sacc[2][2] = {};
#pragma unroll
        for (int kick = 0; kick < 2; ++kick)
#pragma unroll
            for (int it = 0; it < 2; ++it)
#pragma unroll
                for (int jm = 0; jm < 2; ++jm)
                    sacc[it][jm] = __builtin_amdgcn_mfma_f32_16x16x32_bf16(
                        kc[it][kick], qf[jm][kick], sacc[it][jm], 0, 0, 0);
        if (kk < 31) {                             // prefetch next kt chunk (registers)
#pragma unroll
            for (int it = 0; it < 2; ++it)
#pragma unroll
                for (int kick = 0; kick < 2; ++kick)
                    kn[it][kick] = *(const bf16x8*)&kb[(size_t)((kk+1)*32 + it*16 + l15) * 64 + kick*32 + quad*8];
        }
        // ---- epilogue: square, weighted rowsum partial, pack to As (own rows)
#pragma unroll
        for (int it = 0; it < 2; ++it) {
            float4 g = *(const float4*)&Grs[kk * 32 + it * 16 + quad * 4];
#pragma unroll
            for (int jm = 0; jm < 2; ++jm) {
                float v0 = sacc[it][jm][0] * 0.125f + 1e-9f; v0 *= v0;
                float v1 = sacc[it][jm][1] * 0.125f + 1e-9f; v1 *= v1;
                float v2 = sacc[it][jm][2] * 0.125f + 1e-9f; v2 *= v2;
                float v3 = sacc[it][jm][3] * 0.125f + 1e-9f; v3 *= v3;
                partial[jm] += v0 * g.x + v1 * g.y + v2 * g.z + v3 * g.w;
                uint2 pk = { pack2(v0, v1), pack2(v2, v3) };
                *(uint2*)&As[(wm + jm*16 + l15) * 40 + it*16 + quad*4] = pk;
            }
        }
        // ---- agg: wave's 32m x 256n; As handoff is intra-wave (DS in-order)
        bf16x8 af[2];
#pragma unroll
        for (int mf = 0; mf < 2; ++mf)
            af[mf] = *(const bf16x8*)&As[(wm + mf*16 + l15) * 40 + quad*8];
#pragma unroll
        for (int nf = 0; nf < 16; ++nf) {
            bf16x8 bfr = *(const bf16x8*)&Bs[buf][(nf*16 + l15) * 32 + quad*8];
#pragma unroll
            for (int mf = 0; mf < 2; ++mf)
                acc[mf][nf] = __builtin_amdgcn_mfma_f32_16x16x32_bf16(af[mf], bfr, acc[mf][nf], 0, 0, 0);
        }
        // rotate kt register buffers
#pragma unroll
        for (int it = 0; it < 2; ++it)
#pragma unroll
            for (int kick = 0; kick < 2; ++kick)
                kc[it][kick] = kn[it][kick];
    }

    // rowsum: reduce quads (same m, different i-subsets); rows are wave-exclusive
#pragma unroll
    for (int jm = 0; jm < 2; ++jm) {
        partial[jm] += __shfl_xor(partial[jm], 16, 64);
        partial[jm] += __shfl_xor(partial[jm], 32, 64);
    }
    if (quad == 0)
#pragma unroll
        for (int jm = 0; jm < 2; ++jm)
            rsw[wm + jm*16 + l15] = 1.0f / (partial[jm] + 0.001f);
    // intra-wave LDS write->read: DS pipe is in-order per wave, no barrier needed

#pragma unroll
    for (int mf = 0; mf < 2; ++mf) {
        float4 rv = *(const float4*)&rsw[wm + mf * 16 + quad * 4];
        float rva[4] = { rv.x, rv.y, rv.z, rv.w };
#pragma unroll
        for (int r = 0; r < 4; ++r) {
            int m = m0 + wm + mf * 16 + quad * 4 + r;
            float* orow = out + (size_t)m * (BATCH * IN_DIM) + (size_t)b * IN_DIM + n0;
#pragma unroll
            for (int nf = 0; nf < 16; ++nf)
                orow[nf * 16 + l15] = acc[mf][nf][r] * rva[r];
        }
    }
}

// ---------------------------------------------------------------------------
extern "C" void kernel_launch(void* const* d_in, const int* in_sizes, int n_in,
                              void* d_out, int out_size, void* d_ws, size_t ws_size,
                              hipStream_t stream) {
    const float* s  = (const float*)d_in[0];
    const float* G  = (const float*)d_in[1];
    const float* Q  = (const float*)d_in[2];
    const float* Kw = (const float*)d_in[3];
    float* out = (float*)d_out;
    char* ws = (char*)d_ws;

    u16*   qws   = (u16*)(ws);                                    // 2 MB
    u16*   ktws  = (u16*)(ws + (size_t)(2u << 20));               // 2 MB
    u16*   Gbt   = (u16*)(ws + (size_t)(4u << 20));               // 2 MB
    u16*   QT    = (u16*)(ws + (size_t)(6u << 20));               // 128 KB
    u16*   KwT   = (u16*)(ws + (size_t)(6u << 20) + (128u << 10)); // 128 KB
    float* Grsum = (float*)(ws + (size_t)(6u << 20) + (256u << 10)); // 4 KB
    float* Grp   = (float*)(ws + (size_t)(6u << 20) + (260u << 10)); // 64 KB

    prep<<<768, 256, 0, stream>>>(G, Q, Kw, Gbt, Grp, QT, KwT);
    qkt<<<dim3(16, 16, 2), 512, 0, stream>>>(s, QT, KwT, Grp, qws, ktws, Grsum);
    gemm_fused<<<dim3(4, 8, 16), 256, 0, stream>>>(qws, ktws, Gbt, Grsum, out);
}